// Round 1
// baseline (1599.035 us; speedup 1.0000x reference)
//
#include <hip/hip_runtime.h>

typedef unsigned int uint;
typedef unsigned short ushort;
typedef __bf16 bf16_t;
typedef bf16_t bf16x8 __attribute__((ext_vector_type(8)));
typedef ushort ushort8 __attribute__((ext_vector_type(8)));
typedef float f32x4 __attribute__((ext_vector_type(4)));

#define NN 200000
#define EE 600000
#define LL 5
#define GG 2000
#define SCAN_NB 782  // ceil(NN/256)

__device__ __forceinline__ ushort f2bf(float f) {
  uint u = __builtin_bit_cast(uint, f);
  return (ushort)((u + 0x7FFFu + ((u >> 16) & 1u)) >> 16);
}
__device__ __forceinline__ float bf2f(ushort h) {
  return __builtin_bit_cast(float, ((uint)h) << 16);
}
__device__ __forceinline__ float bflo(uint u) {
  return __builtin_bit_cast(float, u << 16);
}
__device__ __forceinline__ float bfhi(uint u) {
  return __builtin_bit_cast(float, u & 0xFFFF0000u);
}

// ---------------- weight swizzle into MFMA B-fragment order ----------------
// B-frag for 16x16x32: lane holds B[k0 + (lane>>4)*8 + j][n0 + (lane&15)], j=0..7
// W1: 5 layers x 4 ktiles x 16 ntiles; W2: 5 x 8 ktiles x 8 ntiles. 512 ushorts/frag.
__global__ void k_swz(const float* __restrict__ W1, const float* __restrict__ W2,
                      ushort* __restrict__ w1s, ushort* __restrict__ w2s) {
  int T = blockIdx.x * 256 + threadIdx.x;
  int lane = T & 63;
  int f = T >> 6;
  bool isW2 = false;
  if (f >= 320) { f -= 320; isW2 = true; }
  int l = f >> 6, rem = f & 63;
  ushort8 o;
  if (!isW2) {
    int kt = rem >> 4, nt = rem & 15;
    int n = nt * 16 + (lane & 15);
    int kbase = kt * 32 + (lane >> 4) * 8;
#pragma unroll
    for (int j = 0; j < 8; ++j) o[j] = f2bf(W1[l * 32768 + (kbase + j) * 256 + n]);
    *(ushort8*)(w1s + f * 512 + lane * 8) = o;
  } else {
    int kt = rem >> 3, nt = rem & 7;
    int n = nt * 16 + (lane & 15);
    int kbase = kt * 32 + (lane >> 4) * 8;
#pragma unroll
    for (int j = 0; j < 8; ++j) o[j] = f2bf(W2[l * 32768 + (kbase + j) * 128 + n]);
    *(ushort8*)(w2s + f * 512 + lane * 8) = o;
  }
}

// ---------------- CSR build (dst is fixed across layers) ----------------
__global__ void k_count(const int* __restrict__ ei, int* __restrict__ counts) {
  int e = blockIdx.x * 256 + threadIdx.x;
  if (e < EE) atomicAdd(&counts[ei[EE + e]], 1);
}

__global__ void k_scanA(const int* __restrict__ counts, int* __restrict__ rowptr,
                        int* __restrict__ bsums) {
  __shared__ int sd[256];
  int tid = threadIdx.x;
  int g = blockIdx.x * 256 + tid;
  int v = (g < NN) ? counts[g] : 0;
  sd[tid] = v;
  __syncthreads();
  for (int o = 1; o < 256; o <<= 1) {
    int t = (tid >= o) ? sd[tid - o] : 0;
    __syncthreads();
    sd[tid] += t;
    __syncthreads();
  }
  if (g < NN) rowptr[g] = sd[tid] - v;  // exclusive within block
  if (tid == 255) bsums[blockIdx.x] = sd[tid];
}

__global__ void k_scanB(int* __restrict__ bsums) {
  __shared__ int sd[1024];
  int tid = threadIdx.x;
  int v = (tid < SCAN_NB) ? bsums[tid] : 0;
  sd[tid] = v;
  __syncthreads();
  for (int o = 1; o < 1024; o <<= 1) {
    int t = (tid >= o) ? sd[tid - o] : 0;
    __syncthreads();
    sd[tid] += t;
    __syncthreads();
  }
  if (tid < SCAN_NB) bsums[tid] = sd[tid] - v;  // exclusive
}

__global__ void k_scanC(int* __restrict__ rowptr, const int* __restrict__ bsums) {
  int g = blockIdx.x * 256 + threadIdx.x;
  if (g < NN) rowptr[g] += bsums[blockIdx.x];
  if (g == 0) rowptr[NN] = EE;
}

// pack src (18 bits) | attr9 (4 bits) per edge slot
__global__ void k_fill(const int* __restrict__ ei, const int* __restrict__ ea,
                       int* __restrict__ cursor, int* __restrict__ eslot) {
  int e = blockIdx.x * 256 + threadIdx.x;
  if (e < EE) {
    int dst = ei[EE + e];
    int src = ei[e];
    int a9 = ea[2 * e] * 3 + ea[2 * e + 1];
    int pos = atomicAdd(&cursor[dst], 1);
    eslot[pos] = src | (a9 << 18);
  }
}

// ---------------- gather / message passing ----------------
// one wave per node; lane handles cols {2*lane, 2*lane+1}; BN affine + relu folded in.
__global__ void k_gather(const int* __restrict__ xidx, const ushort* __restrict__ zin,
                         const float* __restrict__ ee1, const float* __restrict__ ee2,
                         const float* __restrict__ at1, const float* __restrict__ at2,
                         const float* __restrict__ bnscale, const float* __restrict__ bnshift,
                         const int* __restrict__ rowptr, const int* __restrict__ eslot,
                         ushort* __restrict__ aggout, int layer) {
  __shared__ float comb[9 * 128];
  __shared__ float a1s[3 * 128], a2s[3 * 128];
  const int tid = threadIdx.x;
  for (int i = tid; i < 9 * 128; i += 256) {
    int ab = i >> 7, c = i & 127;
    int a = ab / 3, b = ab - a * 3;
    comb[i] = ee1[(layer * 6 + a) * 128 + c] + ee2[(layer * 3 + b) * 128 + c];
  }
  if (layer == 0) {
    for (int i = tid; i < 3 * 128; i += 256) { a1s[i] = at1[i]; a2s[i] = at2[i]; }
  }
  __syncthreads();

  const int lane = tid & 63;
  const int n = blockIdx.x * 4 + (tid >> 6);
  const int c0 = lane * 2;

  float selfc0 = ee1[(layer * 6 + 4) * 128 + c0] + ee2[(layer * 3) * 128 + c0];
  float selfc1 = ee1[(layer * 6 + 4) * 128 + c0 + 1] + ee2[(layer * 3) * 128 + c0 + 1];

  float sc0 = 1.f, sh0 = 0.f, sc1 = 1.f, sh1 = 0.f;
  if (layer > 0) {
    sc0 = bnscale[(layer - 1) * 128 + c0];
    sh0 = bnshift[(layer - 1) * 128 + c0];
    sc1 = bnscale[(layer - 1) * 128 + c0 + 1];
    sh1 = bnshift[(layer - 1) * 128 + c0 + 1];
  }

  float acc0, acc1;
  if (layer == 0) {
    int i0 = xidx[2 * n], i1 = xidx[2 * n + 1];
    acc0 = a1s[i0 * 128 + c0] + a2s[i1 * 128 + c0];
    acc1 = a1s[i0 * 128 + c0 + 1] + a2s[i1 * 128 + c0 + 1];
  } else {
    uint u = ((const uint*)zin)[n * 64 + lane];
    acc0 = fmaxf(fmaf(bflo(u), sc0, sh0), 0.0f);
    acc1 = fmaxf(fmaf(bfhi(u), sc1, sh1), 0.0f);
  }
  acc0 += selfc0;
  acc1 += selfc1;

  const int s = rowptr[n], e = rowptr[n + 1];
  for (int idx = s; idx < e; ++idx) {
    int slot = eslot[idx];
    int src = slot & 0x3FFFF, a9 = slot >> 18;
    float m0, m1;
    if (layer == 0) {
      int i0 = xidx[2 * src], i1 = xidx[2 * src + 1];
      m0 = a1s[i0 * 128 + c0] + a2s[i1 * 128 + c0];
      m1 = a1s[i0 * 128 + c0 + 1] + a2s[i1 * 128 + c0 + 1];
    } else {
      uint u = ((const uint*)zin)[src * 64 + lane];
      m0 = fmaxf(fmaf(bflo(u), sc0, sh0), 0.0f);
      m1 = fmaxf(fmaf(bfhi(u), sc1, sh1), 0.0f);
    }
    acc0 += m0 + comb[a9 * 128 + c0];
    acc1 += m1 + comb[a9 * 128 + c0 + 1];
  }
  uint o = (uint)f2bf(acc0) | ((uint)f2bf(acc1) << 16);
  ((uint*)aggout)[n * 64 + lane] = o;
}

// ---------------- fused MLP: z = relu(A@W1+b1)@W2+b2, in-place on buf ----------------
// block = 4 waves, 64-row tile. Stage1: wave w -> mid cols [64w,64w+64).
// Stage2: wave w -> out cols [32w,32w+32). T1 staged in LDS (stride 264 -> 528B, 16B aligned).
__global__ __launch_bounds__(256) void k_gemm(ushort* __restrict__ buf,
                                              const ushort* __restrict__ w1s,
                                              const ushort* __restrict__ w2s,
                                              const float* __restrict__ b1,
                                              const float* __restrict__ b2, int layer) {
  __shared__ __align__(16) ushort T1[64 * 264];
  const int tid = threadIdx.x;
  const int w = tid >> 6, lane = tid & 63;
  const int lm = lane & 15, q = lane >> 4;
  const int row0 = blockIdx.x * 64;

  f32x4 acc[4][4] = {};
  const ushort* w1b = w1s + layer * 64 * 512;
#pragma unroll
  for (int kt = 0; kt < 4; ++kt) {
    bf16x8 a[4], b[4];
#pragma unroll
    for (int mt = 0; mt < 4; ++mt) {
      const ushort* p = buf + (row0 + mt * 16 + lm) * 128 + kt * 32 + q * 8;
      a[mt] = __builtin_bit_cast(bf16x8, *(const ushort8*)p);
    }
#pragma unroll
    for (int nt = 0; nt < 4; ++nt) {
      const ushort* p = w1b + (kt * 16 + w * 4 + nt) * 512 + lane * 8;
      b[nt] = __builtin_bit_cast(bf16x8, *(const ushort8*)p);
    }
#pragma unroll
    for (int mt = 0; mt < 4; ++mt)
#pragma unroll
      for (int nt = 0; nt < 4; ++nt)
        acc[mt][nt] = __builtin_amdgcn_mfma_f32_16x16x32_bf16(a[mt], b[nt], acc[mt][nt], 0, 0, 0);
  }
  // bias + relu -> T1 (bf16)
#pragma unroll
  for (int nt = 0; nt < 4; ++nt) {
    int n = w * 64 + nt * 16 + lm;
    float bias = b1[layer * 256 + n];
#pragma unroll
    for (int mt = 0; mt < 4; ++mt)
#pragma unroll
      for (int r = 0; r < 4; ++r) {
        float v = fmaxf(acc[mt][nt][r] + bias, 0.0f);
        T1[(mt * 16 + q * 4 + r) * 264 + n] = f2bf(v);
      }
  }
  __syncthreads();

  f32x4 acc2[4][2] = {};
  const ushort* w2b = w2s + layer * 64 * 512;
#pragma unroll
  for (int kt = 0; kt < 8; ++kt) {
    bf16x8 a[4], b[2];
#pragma unroll
    for (int mt = 0; mt < 4; ++mt) {
      const ushort* p = T1 + (mt * 16 + lm) * 264 + kt * 32 + q * 8;
      a[mt] = __builtin_bit_cast(bf16x8, *(const ushort8*)p);
    }
#pragma unroll
    for (int nt = 0; nt < 2; ++nt) {
      const ushort* p = w2b + (kt * 8 + w * 2 + nt) * 512 + lane * 8;
      b[nt] = __builtin_bit_cast(bf16x8, *(const ushort8*)p);
    }
#pragma unroll
    for (int mt = 0; mt < 4; ++mt)
#pragma unroll
      for (int nt = 0; nt < 2; ++nt)
        acc2[mt][nt] = __builtin_amdgcn_mfma_f32_16x16x32_bf16(a[mt], b[nt], acc2[mt][nt], 0, 0, 0);
  }
  __syncthreads();
  // repack z into LDS (alias T1) for coalesced global store
  ushort* ldsZ = T1;  // 64 x 136
#pragma unroll
  for (int nt = 0; nt < 2; ++nt) {
    int n = w * 32 + nt * 16 + lm;
    float bias = b2[layer * 128 + n];
#pragma unroll
    for (int mt = 0; mt < 4; ++mt)
#pragma unroll
      for (int r = 0; r < 4; ++r)
        ldsZ[(mt * 16 + q * 4 + r) * 136 + n] = f2bf(acc2[mt][nt][r] + bias);
  }
  __syncthreads();
  uint* zout = (uint*)buf;
  for (int i = tid; i < 64 * 64; i += 256) {
    int row = i >> 6, cp = i & 63;
    uint v = *(const uint*)&ldsZ[row * 136 + cp * 2];
    zout[(row0 + row) * 64 + cp] = v;
  }
}

// ---------------- BN statistics over z (bf16) ----------------
__global__ void k_stats(const ushort* __restrict__ z, float* __restrict__ stats, int layer) {
  __shared__ float ssum[256], ssq[256];
  int tid = threadIdx.x;
  int col = tid & 127, half = tid >> 7;
  float s = 0.f, qq = 0.f;
  for (int r = blockIdx.x * 2 + half; r < NN; r += gridDim.x * 2) {
    float v = bf2f(z[(size_t)r * 128 + col]);
    s += v;
    qq += v * v;
  }
  ssum[tid] = s;
  ssq[tid] = qq;
  __syncthreads();
  if (tid < 128) {
    s = ssum[tid] + ssum[tid + 128];
    qq = ssq[tid] + ssq[tid + 128];
    atomicAdd(&stats[layer * 256 + col], s);
    atomicAdd(&stats[layer * 256 + 128 + col], qq);
  }
}

__global__ void k_bnparam(const float* __restrict__ stats, const float* __restrict__ gamma,
                          const float* __restrict__ beta, float* __restrict__ bnscale,
                          float* __restrict__ bnshift, int layer) {
  int c = threadIdx.x;
  float mu = stats[layer * 256 + c] * (1.0f / NN);
  float var = stats[layer * 256 + 128 + c] * (1.0f / NN) - mu * mu;
  float sc = gamma[layer * 128 + c] * rsqrtf(var + 1e-5f);
  bnscale[layer * 128 + c] = sc;
  bnshift[layer * 128 + c] = beta[layer * 128 + c] - mu * sc;
}

// ---------------- pooling: out[g] += sum_n dot(affine(z4[n]), Wp) ----------------
__global__ void k_outinit(float* __restrict__ out, const float* __restrict__ bp) {
  int g = blockIdx.x * 256 + threadIdx.x;
  if (g < GG) out[g] = bp[0];
}

__global__ void k_pool(const ushort* __restrict__ z, const float* __restrict__ bnscale,
                       const float* __restrict__ bnshift, const int* __restrict__ batch,
                       const float* __restrict__ Wp, float* __restrict__ out) {
  const int tid = threadIdx.x, lane = tid & 63;
  const int n = blockIdx.x * 4 + (tid >> 6);
  const int c0 = lane * 2;
  uint u = ((const uint*)z)[n * 64 + lane];
  float v0 = fmaf(bflo(u), bnscale[4 * 128 + c0], bnshift[4 * 128 + c0]);
  float v1 = fmaf(bfhi(u), bnscale[4 * 128 + c0 + 1], bnshift[4 * 128 + c0 + 1]);
  float sum = v0 * Wp[c0] + v1 * Wp[c0 + 1];
#pragma unroll
  for (int off = 32; off > 0; off >>= 1) sum += __shfl_down(sum, off, 64);
  if (lane == 0) atomicAdd(&out[batch[n]], sum);
}

extern "C" void kernel_launch(void* const* d_in, const int* in_sizes, int n_in,
                              void* d_out, int out_size, void* d_ws, size_t ws_size,
                              hipStream_t stream) {
  (void)in_sizes; (void)n_in; (void)out_size; (void)ws_size;
  const int* xidx = (const int*)d_in[0];
  const int* eidx = (const int*)d_in[1];
  const int* eattr = (const int*)d_in[2];
  const int* batch = (const int*)d_in[3];
  const float* at1 = (const float*)d_in[4];
  const float* at2 = (const float*)d_in[5];
  const float* ee1 = (const float*)d_in[6];
  const float* ee2 = (const float*)d_in[7];
  const float* W1 = (const float*)d_in[8];
  const float* b1 = (const float*)d_in[9];
  const float* W2 = (const float*)d_in[10];
  const float* b2 = (const float*)d_in[11];
  const float* gamma = (const float*)d_in[12];
  const float* beta = (const float*)d_in[13];
  const float* Wp = (const float*)d_in[14];
  const float* bp = (const float*)d_in[15];
  float* out = (float*)d_out;

  char* ws = (char*)d_ws;
  size_t off = 0;
  auto alloc = [&](size_t bytes) -> void* {
    void* p = ws + off;
    off = (off + bytes + 255) & ~(size_t)255;
    return p;
  };
  ushort* bufA = (ushort*)alloc((size_t)NN * 128 * 2);
  ushort* bufB = (ushort*)alloc((size_t)NN * 128 * 2);
  ushort* w1s = (ushort*)alloc(320 * 512 * 2);
  ushort* w2s = (ushort*)alloc(320 * 512 * 2);
  int* rowptr = (int*)alloc((NN + 1) * 4);
  int* cursor = (int*)alloc((size_t)NN * 4);
  int* eslot = (int*)alloc((size_t)EE * 4);
  int* bsums = (int*)alloc(1024 * 4);
  float* stats = (float*)alloc(LL * 256 * 4);
  float* bnscale = (float*)alloc(LL * 128 * 4);
  float* bnshift = (float*)alloc(LL * 128 * 4);

  hipMemsetAsync(cursor, 0, (size_t)NN * 4, stream);  // cursor doubles as counts
  hipMemsetAsync(stats, 0, LL * 256 * 4, stream);
  k_swz<<<160, 256, 0, stream>>>(W1, W2, w1s, w2s);
  k_count<<<(EE + 255) / 256, 256, 0, stream>>>(eidx, cursor);
  k_scanA<<<SCAN_NB, 256, 0, stream>>>(cursor, rowptr, bsums);
  k_scanB<<<1, 1024, 0, stream>>>(bsums);
  k_scanC<<<SCAN_NB, 256, 0, stream>>>(rowptr, bsums);
  hipMemcpyAsync(cursor, rowptr, (size_t)NN * 4, hipMemcpyDeviceToDevice, stream);
  k_fill<<<(EE + 255) / 256, 256, 0, stream>>>(eidx, eattr, cursor, eslot);

  for (int l = 0; l < LL; ++l) {
    ushort* dst = (l & 1) ? bufB : bufA;
    ushort* srcb = (l & 1) ? bufA : bufB;  // z_{l-1}
    k_gather<<<NN / 4, 256, 0, stream>>>(xidx, (l == 0) ? (const ushort*)nullptr : srcb,
                                         ee1, ee2, at1, at2, bnscale, bnshift, rowptr,
                                         eslot, dst, l);
    k_gemm<<<NN / 64, 256, 0, stream>>>(dst, w1s, w2s, b1, b2, l);
    k_stats<<<512, 256, 0, stream>>>(dst, stats, l);
    k_bnparam<<<1, 128, 0, stream>>>(stats, gamma, beta, bnscale, bnshift, l);
  }
  k_outinit<<<(GG + 255) / 256, 256, 0, stream>>>(out, bp);
  k_pool<<<NN / 4, 256, 0, stream>>>(bufA, bnscale, bnshift, batch, Wp, out);
}

// Round 2
// 861.413 us; speedup vs baseline: 1.8563x; 1.8563x over previous
//
#include <hip/hip_runtime.h>

typedef unsigned int uint;
typedef unsigned short ushort;
typedef __bf16 bf16_t;
typedef bf16_t bf16x8 __attribute__((ext_vector_type(8)));
typedef ushort ushort8 __attribute__((ext_vector_type(8)));
typedef float f32x4 __attribute__((ext_vector_type(4)));

#define NN 200000
#define EE 600000
#define LL 5
#define GG 2000
#define SCAN_NB 782  // ceil(NN/256)

__device__ __forceinline__ ushort f2bf(float f) {
  uint u = __builtin_bit_cast(uint, f);
  return (ushort)((u + 0x7FFFu + ((u >> 16) & 1u)) >> 16);
}
__device__ __forceinline__ float bflo(uint u) {
  return __builtin_bit_cast(float, u << 16);
}
__device__ __forceinline__ float bfhi(uint u) {
  return __builtin_bit_cast(float, u & 0xFFFF0000u);
}

// ---------------- weight swizzle into MFMA B-fragment order ----------------
__global__ void k_swz(const float* __restrict__ W1, const float* __restrict__ W2,
                      ushort* __restrict__ w1s, ushort* __restrict__ w2s) {
  int T = blockIdx.x * 256 + threadIdx.x;
  int lane = T & 63;
  int f = T >> 6;
  bool isW2 = false;
  if (f >= 320) { f -= 320; isW2 = true; }
  int l = f >> 6, rem = f & 63;
  ushort8 o;
  if (!isW2) {
    int kt = rem >> 4, nt = rem & 15;
    int n = nt * 16 + (lane & 15);
    int kbase = kt * 32 + (lane >> 4) * 8;
#pragma unroll
    for (int j = 0; j < 8; ++j) o[j] = f2bf(W1[l * 32768 + (kbase + j) * 256 + n]);
    *(ushort8*)(w1s + f * 512 + lane * 8) = o;
  } else {
    int kt = rem >> 3, nt = rem & 7;
    int n = nt * 16 + (lane & 15);
    int kbase = kt * 32 + (lane >> 4) * 8;
#pragma unroll
    for (int j = 0; j < 8; ++j) o[j] = f2bf(W2[l * 32768 + (kbase + j) * 128 + n]);
    *(ushort8*)(w2s + f * 512 + lane * 8) = o;
  }
}

// ---------------- constant tables: comb[5][9][128], selfv[5][128], atomc[9][128] ----
__global__ void k_tables(const float* __restrict__ ee1, const float* __restrict__ ee2,
                         const float* __restrict__ at1, const float* __restrict__ at2,
                         float* __restrict__ tab) {
  int i = blockIdx.x * 256 + threadIdx.x;
  if (i < 5760) {  // comb
    int l = i / 1152, rem = i % 1152;
    int ab = rem >> 7, c = rem & 127;
    int a = ab / 3, b = ab - a * 3;
    tab[i] = ee1[(l * 6 + a) * 128 + c] + ee2[(l * 3 + b) * 128 + c];
  } else if (i < 6400) {  // selfv
    int j = i - 5760;
    int l = j >> 7, c = j & 127;
    tab[i] = ee1[(l * 6 + 4) * 128 + c] + ee2[(l * 3 + 0) * 128 + c];
  } else if (i < 7552) {  // atomc
    int j = i - 6400;
    int ab = j >> 7, c = j & 127;
    int a = ab / 3, b = ab - a * 3;
    tab[i] = at1[a * 128 + c] + at2[b * 128 + c];
  }
}

__global__ void k_xcode(const int* __restrict__ xidx, int* __restrict__ xcode) {
  int n = blockIdx.x * 256 + threadIdx.x;
  if (n < NN) xcode[n] = xidx[2 * n] * 3 + xidx[2 * n + 1];
}

// ---------------- CSR build (dst is fixed across layers) ----------------
__global__ void k_count(const int* __restrict__ ei, int* __restrict__ counts) {
  int e = blockIdx.x * 256 + threadIdx.x;
  if (e < EE) atomicAdd(&counts[ei[EE + e]], 1);
}

__global__ void k_scanA(const int* __restrict__ counts, int* __restrict__ rowptr,
                        int* __restrict__ bsums) {
  __shared__ int sd[256];
  int tid = threadIdx.x;
  int g = blockIdx.x * 256 + tid;
  int v = (g < NN) ? counts[g] : 0;
  sd[tid] = v;
  __syncthreads();
  for (int o = 1; o < 256; o <<= 1) {
    int t = (tid >= o) ? sd[tid - o] : 0;
    __syncthreads();
    sd[tid] += t;
    __syncthreads();
  }
  if (g < NN) rowptr[g] = sd[tid] - v;
  if (tid == 255) bsums[blockIdx.x] = sd[tid];
}

__global__ void k_scanB(int* __restrict__ bsums) {
  __shared__ int sd[1024];
  int tid = threadIdx.x;
  int v = (tid < SCAN_NB) ? bsums[tid] : 0;
  sd[tid] = v;
  __syncthreads();
  for (int o = 1; o < 1024; o <<= 1) {
    int t = (tid >= o) ? sd[tid - o] : 0;
    __syncthreads();
    sd[tid] += t;
    __syncthreads();
  }
  if (tid < SCAN_NB) bsums[tid] = sd[tid] - v;
}

__global__ void k_scanC(int* __restrict__ rowptr, const int* __restrict__ bsums) {
  int g = blockIdx.x * 256 + threadIdx.x;
  if (g < NN) rowptr[g] += bsums[blockIdx.x];
  if (g == 0) rowptr[NN] = EE;
}

// pack src (18b) | a9 (4b) | xcode_src (4b)
__global__ void k_fill(const int* __restrict__ ei, const int* __restrict__ ea,
                       const int* __restrict__ xcode, int* __restrict__ cursor,
                       int* __restrict__ eslot) {
  int e = blockIdx.x * 256 + threadIdx.x;
  if (e < EE) {
    int dst = ei[EE + e];
    int src = ei[e];
    int a9 = ea[2 * e] * 3 + ea[2 * e + 1];
    int sc = xcode[src];
    int pos = atomicAdd(&cursor[dst], 1);
    eslot[pos] = src | (a9 << 18) | (sc << 22);
  }
}

// ---------------- gather / message passing ----------------
// 4 waves/block, 16 consecutive nodes per wave. Tables read from global (L1-hot).
__global__ __launch_bounds__(256) void k_gather(
    const int* __restrict__ xcode, const ushort* __restrict__ zin,
    const float* __restrict__ tab, const float* __restrict__ bnscale,
    const float* __restrict__ bnshift, const int* __restrict__ rowptr,
    const int* __restrict__ eslot, ushort* __restrict__ aggout, int layer) {
  const int tid = threadIdx.x;
  const int w = tid >> 6, lane = tid & 63;
  const int nb = blockIdx.x * 64 + w * 16;

  const float2* combL = (const float2*)(tab + (size_t)layer * 9 * 128);
  const float2* atomcp = (const float2*)(tab + 6400);
  float2 sf = ((const float2*)(tab + 5760 + layer * 128))[lane];

  float sc0 = 0.f, sh0 = 0.f, sc1 = 0.f, sh1 = 0.f;
  if (layer > 0) {
    float2 scv = ((const float2*)(bnscale + (layer - 1) * 128))[lane];
    float2 shv = ((const float2*)(bnshift + (layer - 1) * 128))[lane];
    sc0 = scv.x; sc1 = scv.y; sh0 = shv.x; sh1 = shv.y;
  }

  int rp = 0;
  if (lane <= 16) rp = rowptr[nb + lane];
  const uint* z32 = (const uint*)zin;
  uint* agg32 = (uint*)aggout;

  for (int i = 0; i < 16; ++i) {
    const int n = nb + i;
    const int s = __shfl(rp, i), e2 = __shfl(rp, i + 1);
    float acc0, acc1;
    if (layer == 0) {
      int code = xcode[n];
      float2 h = atomcp[code * 64 + lane];
      acc0 = h.x + sf.x;
      acc1 = h.y + sf.y;
    } else {
      uint u = z32[(size_t)n * 64 + lane];
      acc0 = fmaxf(fmaf(bflo(u), sc0, sh0), 0.f) + sf.x;
      acc1 = fmaxf(fmaf(bfhi(u), sc1, sh1), 0.f) + sf.y;
    }
    for (int base = s; base < e2; base += 64) {
      int m = e2 - base;
      if (m > 64) m = 64;
      int slot = (lane < m) ? eslot[base + lane] : 0;
      for (int j = 0; j < m; ++j) {
        int sl = __shfl(slot, j);
        int src = sl & 0x3FFFF;
        int a9 = (sl >> 18) & 15;
        float2 cb = combL[a9 * 64 + lane];
        float m0, m1;
        if (layer == 0) {
          int scode = (sl >> 22) & 15;
          float2 h = atomcp[scode * 64 + lane];
          m0 = h.x;
          m1 = h.y;
        } else {
          uint u = z32[(size_t)src * 64 + lane];
          m0 = fmaxf(fmaf(bflo(u), sc0, sh0), 0.f);
          m1 = fmaxf(fmaf(bfhi(u), sc1, sh1), 0.f);
        }
        acc0 += m0 + cb.x;
        acc1 += m1 + cb.y;
      }
    }
    uint o = (uint)f2bf(acc0) | ((uint)f2bf(acc1) << 16);
    agg32[(size_t)n * 64 + lane] = o;
  }
}

// ---------------- fused MLP + BN-stats epilogue, in-place on buf ----------------
__global__ __launch_bounds__(256) void k_gemm(ushort* __restrict__ buf,
                                              const ushort* __restrict__ w1s,
                                              const ushort* __restrict__ w2s,
                                              const float* __restrict__ b1,
                                              const float* __restrict__ b2,
                                              float* __restrict__ stats, int layer) {
  __shared__ __align__(16) ushort T1[64 * 264];
  const int tid = threadIdx.x;
  const int w = tid >> 6, lane = tid & 63;
  const int lm = lane & 15, q = lane >> 4;
  const int row0 = blockIdx.x * 64;

  f32x4 acc[4][4] = {};
  const ushort* w1b = w1s + layer * 64 * 512;
#pragma unroll
  for (int kt = 0; kt < 4; ++kt) {
    bf16x8 a[4], b[4];
#pragma unroll
    for (int mt = 0; mt < 4; ++mt) {
      const ushort* p = buf + (size_t)(row0 + mt * 16 + lm) * 128 + kt * 32 + q * 8;
      a[mt] = __builtin_bit_cast(bf16x8, *(const ushort8*)p);
    }
#pragma unroll
    for (int nt = 0; nt < 4; ++nt) {
      const ushort* p = w1b + (kt * 16 + w * 4 + nt) * 512 + lane * 8;
      b[nt] = __builtin_bit_cast(bf16x8, *(const ushort8*)p);
    }
#pragma unroll
    for (int mt = 0; mt < 4; ++mt)
#pragma unroll
      for (int nt = 0; nt < 4; ++nt)
        acc[mt][nt] = __builtin_amdgcn_mfma_f32_16x16x32_bf16(a[mt], b[nt], acc[mt][nt], 0, 0, 0);
  }
#pragma unroll
  for (int nt = 0; nt < 4; ++nt) {
    int n = w * 64 + nt * 16 + lm;
    float bias = b1[layer * 256 + n];
#pragma unroll
    for (int mt = 0; mt < 4; ++mt)
#pragma unroll
      for (int r = 0; r < 4; ++r) {
        float v = fmaxf(acc[mt][nt][r] + bias, 0.0f);
        T1[(mt * 16 + q * 4 + r) * 264 + n] = f2bf(v);
      }
  }
  __syncthreads();

  f32x4 acc2[4][2] = {};
  const ushort* w2b = w2s + layer * 64 * 512;
#pragma unroll
  for (int kt = 0; kt < 8; ++kt) {
    bf16x8 a[4], b[2];
#pragma unroll
    for (int mt = 0; mt < 4; ++mt) {
      const ushort* p = T1 + (mt * 16 + lm) * 264 + kt * 32 + q * 8;
      a[mt] = __builtin_bit_cast(bf16x8, *(const ushort8*)p);
    }
#pragma unroll
    for (int nt = 0; nt < 2; ++nt) {
      const ushort* p = w2b + (kt * 8 + w * 2 + nt) * 512 + lane * 8;
      b[nt] = __builtin_bit_cast(bf16x8, *(const ushort8*)p);
    }
#pragma unroll
    for (int mt = 0; mt < 4; ++mt)
#pragma unroll
      for (int nt = 0; nt < 2; ++nt)
        acc2[mt][nt] = __builtin_amdgcn_mfma_f32_16x16x32_bf16(a[mt], b[nt], acc2[mt][nt], 0, 0, 0);
  }
  __syncthreads();
  ushort* ldsZ = T1;  // 64 x 136 bf16
  float ssum[2], ssq[2];
#pragma unroll
  for (int nt = 0; nt < 2; ++nt) {
    int n = w * 32 + nt * 16 + lm;
    float bias = b2[layer * 128 + n];
    ssum[nt] = 0.f;
    ssq[nt] = 0.f;
#pragma unroll
    for (int mt = 0; mt < 4; ++mt)
#pragma unroll
      for (int r = 0; r < 4; ++r) {
        float v = acc2[mt][nt][r] + bias;
        ldsZ[(mt * 16 + q * 4 + r) * 136 + n] = f2bf(v);
        ssum[nt] += v;
        ssq[nt] += v * v;
      }
    // reduce over the 4 q-groups (lanes ^16, ^32) -> full 64-row column sums
    ssum[nt] += __shfl_xor(ssum[nt], 16, 64);
    ssum[nt] += __shfl_xor(ssum[nt], 32, 64);
    ssq[nt] += __shfl_xor(ssq[nt], 16, 64);
    ssq[nt] += __shfl_xor(ssq[nt], 32, 64);
  }
  if (lane < 16) {
    int cp = blockIdx.x & 15;
    float* sb = stats + (size_t)(layer * 16 + cp) * 256;
#pragma unroll
    for (int nt = 0; nt < 2; ++nt) {
      int col = w * 32 + nt * 16 + lane;
      atomicAdd(&sb[col], ssum[nt]);
      atomicAdd(&sb[128 + col], ssq[nt]);
    }
  }
  __syncthreads();
  uint* zout = (uint*)buf;
  for (int i = tid; i < 64 * 64; i += 256) {
    int row = i >> 6, cpx = i & 63;
    uint v = *(const uint*)&ldsZ[row * 136 + cpx * 2];
    zout[(size_t)(row0 + row) * 64 + cpx] = v;
  }
}

__global__ void k_bnparam(const float* __restrict__ stats, const float* __restrict__ gamma,
                          const float* __restrict__ beta, float* __restrict__ bnscale,
                          float* __restrict__ bnshift, int layer) {
  int c = threadIdx.x;
  float s = 0.f, qv = 0.f;
  for (int cp = 0; cp < 16; ++cp) {
    const float* sb = stats + (size_t)(layer * 16 + cp) * 256;
    s += sb[c];
    qv += sb[128 + c];
  }
  float mu = s * (1.0f / NN);
  float var = qv * (1.0f / NN) - mu * mu;
  float sc = gamma[layer * 128 + c] * rsqrtf(var + 1e-5f);
  bnscale[layer * 128 + c] = sc;
  bnshift[layer * 128 + c] = beta[layer * 128 + c] - mu * sc;
}

// ---------------- pooling with segmented running sum (batch sorted) ----------------
__global__ void k_outinit(float* __restrict__ out, const float* __restrict__ bp) {
  int g = blockIdx.x * 256 + threadIdx.x;
  if (g < GG) out[g] = bp[0];
}

__global__ __launch_bounds__(256) void k_pool(const ushort* __restrict__ z,
                                              const float* __restrict__ bnscale,
                                              const float* __restrict__ bnshift,
                                              const int* __restrict__ batch,
                                              const float* __restrict__ Wp,
                                              float* __restrict__ out) {
  const int tid = threadIdx.x;
  const int w = tid >> 6, lane = tid & 63;
  const int nb = blockIdx.x * 64 + w * 16;
  float2 wp = ((const float2*)Wp)[lane];
  float2 scv = ((const float2*)(bnscale + 4 * 128))[lane];
  float2 shv = ((const float2*)(bnshift + 4 * 128))[lane];
  const uint* z32 = (const uint*)z;
  int bb = (lane < 16) ? batch[nb + lane] : 0;
  int curb = __shfl(bb, 0);
  float run = 0.f;
#pragma unroll
  for (int i = 0; i < 16; ++i) {
    int b = __shfl(bb, i);
    uint u = z32[(size_t)(nb + i) * 64 + lane];
    float dot = fmaf(bflo(u), scv.x, shv.x) * wp.x + fmaf(bfhi(u), scv.y, shv.y) * wp.y;
#pragma unroll
    for (int off = 32; off > 0; off >>= 1) dot += __shfl_xor(dot, off, 64);
    if (b != curb) {
      if (lane == 0) atomicAdd(&out[curb], run);
      run = 0.f;
      curb = b;
    }
    run += dot;
  }
  if (lane == 0) atomicAdd(&out[curb], run);
}

extern "C" void kernel_launch(void* const* d_in, const int* in_sizes, int n_in,
                              void* d_out, int out_size, void* d_ws, size_t ws_size,
                              hipStream_t stream) {
  (void)in_sizes; (void)n_in; (void)out_size; (void)ws_size;
  const int* xidx = (const int*)d_in[0];
  const int* eidx = (const int*)d_in[1];
  const int* eattr = (const int*)d_in[2];
  const int* batch = (const int*)d_in[3];
  const float* at1 = (const float*)d_in[4];
  const float* at2 = (const float*)d_in[5];
  const float* ee1 = (const float*)d_in[6];
  const float* ee2 = (const float*)d_in[7];
  const float* W1 = (const float*)d_in[8];
  const float* b1 = (const float*)d_in[9];
  const float* W2 = (const float*)d_in[10];
  const float* b2 = (const float*)d_in[11];
  const float* gamma = (const float*)d_in[12];
  const float* beta = (const float*)d_in[13];
  const float* Wp = (const float*)d_in[14];
  const float* bp = (const float*)d_in[15];
  float* out = (float*)d_out;

  char* ws = (char*)d_ws;
  size_t off = 0;
  auto alloc = [&](size_t bytes) -> void* {
    void* p = ws + off;
    off = (off + bytes + 255) & ~(size_t)255;
    return p;
  };
  ushort* bufA = (ushort*)alloc((size_t)NN * 128 * 2);
  ushort* bufB = (ushort*)alloc((size_t)NN * 128 * 2);
  ushort* w1s = (ushort*)alloc(320 * 512 * 2);
  ushort* w2s = (ushort*)alloc(320 * 512 * 2);
  int* rowptr = (int*)alloc((NN + 1) * 4);
  int* cursor = (int*)alloc((size_t)NN * 4);
  int* eslot = (int*)alloc((size_t)EE * 4);
  int* bsums = (int*)alloc(1024 * 4);
  float* tab = (float*)alloc(7552 * 4);
  int* xcode = (int*)alloc((size_t)NN * 4);
  float* stats = (float*)alloc((size_t)LL * 16 * 256 * 4);
  float* bnscale = (float*)alloc(LL * 128 * 4);
  float* bnshift = (float*)alloc(LL * 128 * 4);

  hipMemsetAsync(cursor, 0, (size_t)NN * 4, stream);
  hipMemsetAsync(stats, 0, (size_t)LL * 16 * 256 * 4, stream);
  k_swz<<<160, 256, 0, stream>>>(W1, W2, w1s, w2s);
  k_tables<<<30, 256, 0, stream>>>(ee1, ee2, at1, at2, tab);
  k_xcode<<<(NN + 255) / 256, 256, 0, stream>>>(xidx, xcode);
  k_outinit<<<(GG + 255) / 256, 256, 0, stream>>>(out, bp);
  k_count<<<(EE + 255) / 256, 256, 0, stream>>>(eidx, cursor);
  k_scanA<<<SCAN_NB, 256, 0, stream>>>(cursor, rowptr, bsums);
  k_scanB<<<1, 1024, 0, stream>>>(bsums);
  k_scanC<<<SCAN_NB, 256, 0, stream>>>(rowptr, bsums);
  hipMemcpyAsync(cursor, rowptr, (size_t)NN * 4, hipMemcpyDeviceToDevice, stream);
  k_fill<<<(EE + 255) / 256, 256, 0, stream>>>(eidx, eattr, xcode, cursor, eslot);

  for (int l = 0; l < LL; ++l) {
    ushort* dst = (l & 1) ? bufB : bufA;
    ushort* srcb = (l & 1) ? bufA : bufB;  // z_{l-1}
    k_gather<<<NN / 64, 256, 0, stream>>>(xcode, (l == 0) ? bufA : srcb, tab, bnscale,
                                          bnshift, rowptr, eslot, dst, l);
    k_gemm<<<NN / 64, 256, 0, stream>>>(dst, w1s, w2s, b1, b2, stats, l);
    k_bnparam<<<1, 128, 0, stream>>>(stats, gamma, beta, bnscale, bnshift, l);
  }
  k_pool<<<NN / 64, 256, 0, stream>>>(bufA, bnscale, bnshift, batch, Wp, out);
}

// Round 3
// 687.900 us; speedup vs baseline: 2.3245x; 1.2522x over previous
//
#include <hip/hip_runtime.h>

typedef unsigned int uint;
typedef unsigned short ushort;
typedef __bf16 bf16_t;
typedef bf16_t bf16x8 __attribute__((ext_vector_type(8)));
typedef ushort ushort8 __attribute__((ext_vector_type(8)));
typedef float f32x4 __attribute__((ext_vector_type(4)));

#define NN 200000
#define EE 600000
#define LL 5
#define GG 2000
#define SCAN_NB 782  // ceil(NN/256)

__device__ __forceinline__ ushort f2bf(float f) {
  uint u = __builtin_bit_cast(uint, f);
  return (ushort)((u + 0x7FFFu + ((u >> 16) & 1u)) >> 16);
}
__device__ __forceinline__ float bflo(uint u) {
  return __builtin_bit_cast(float, u << 16);
}
__device__ __forceinline__ float bfhi(uint u) {
  return __builtin_bit_cast(float, u & 0xFFFF0000u);
}

// ---------------- weight swizzle into MFMA B-fragment order ----------------
__global__ void k_swz(const float* __restrict__ W1, const float* __restrict__ W2,
                      ushort* __restrict__ w1s, ushort* __restrict__ w2s) {
  int T = blockIdx.x * 256 + threadIdx.x;
  int lane = T & 63;
  int f = T >> 6;
  bool isW2 = false;
  if (f >= 320) { f -= 320; isW2 = true; }
  int l = f >> 6, rem = f & 63;
  ushort8 o;
  if (!isW2) {
    int kt = rem >> 4, nt = rem & 15;
    int n = nt * 16 + (lane & 15);
    int kbase = kt * 32 + (lane >> 4) * 8;
#pragma unroll
    for (int j = 0; j < 8; ++j) o[j] = f2bf(W1[l * 32768 + (kbase + j) * 256 + n]);
    *(ushort8*)(w1s + f * 512 + lane * 8) = o;
  } else {
    int kt = rem >> 3, nt = rem & 7;
    int n = nt * 16 + (lane & 15);
    int kbase = kt * 32 + (lane >> 4) * 8;
#pragma unroll
    for (int j = 0; j < 8; ++j) o[j] = f2bf(W2[l * 32768 + (kbase + j) * 128 + n]);
    *(ushort8*)(w2s + f * 512 + lane * 8) = o;
  }
}

// ---------------- constant tables: comb[5][9][128], selfv[5][128], atomc[9][128] ----
__global__ void k_tables(const float* __restrict__ ee1, const float* __restrict__ ee2,
                         const float* __restrict__ at1, const float* __restrict__ at2,
                         float* __restrict__ tab) {
  int i = blockIdx.x * 256 + threadIdx.x;
  if (i < 5760) {  // comb
    int l = i / 1152, rem = i % 1152;
    int ab = rem >> 7, c = rem & 127;
    int a = ab / 3, b = ab - a * 3;
    tab[i] = ee1[(l * 6 + a) * 128 + c] + ee2[(l * 3 + b) * 128 + c];
  } else if (i < 6400) {  // selfv
    int j = i - 5760;
    int l = j >> 7, c = j & 127;
    tab[i] = ee1[(l * 6 + 4) * 128 + c] + ee2[(l * 3 + 0) * 128 + c];
  } else if (i < 7552) {  // atomc
    int j = i - 6400;
    int ab = j >> 7, c = j & 127;
    int a = ab / 3, b = ab - a * 3;
    tab[i] = at1[a * 128 + c] + at2[b * 128 + c];
  }
}

__global__ void k_xcode(const int* __restrict__ xidx, int* __restrict__ xcode) {
  int n = blockIdx.x * 256 + threadIdx.x;
  if (n < NN) xcode[n] = xidx[2 * n] * 3 + xidx[2 * n + 1];
}

// ---------------- CSR build (dst is fixed across layers) ----------------
__global__ void k_count(const int* __restrict__ ei, int* __restrict__ counts) {
  int e = blockIdx.x * 256 + threadIdx.x;
  if (e < EE) atomicAdd(&counts[ei[EE + e]], 1);
}

__global__ void k_scanA(const int* __restrict__ counts, int* __restrict__ rowptr,
                        int* __restrict__ bsums) {
  __shared__ int sd[256];
  int tid = threadIdx.x;
  int g = blockIdx.x * 256 + tid;
  int v = (g < NN) ? counts[g] : 0;
  sd[tid] = v;
  __syncthreads();
  for (int o = 1; o < 256; o <<= 1) {
    int t = (tid >= o) ? sd[tid - o] : 0;
    __syncthreads();
    sd[tid] += t;
    __syncthreads();
  }
  if (g < NN) rowptr[g] = sd[tid] - v;
  if (tid == 255) bsums[blockIdx.x] = sd[tid];
}

__global__ void k_scanB(int* __restrict__ bsums) {
  __shared__ int sd[1024];
  int tid = threadIdx.x;
  int v = (tid < SCAN_NB) ? bsums[tid] : 0;
  sd[tid] = v;
  __syncthreads();
  for (int o = 1; o < 1024; o <<= 1) {
    int t = (tid >= o) ? sd[tid - o] : 0;
    __syncthreads();
    sd[tid] += t;
    __syncthreads();
  }
  if (tid < SCAN_NB) bsums[tid] = sd[tid] - v;
}

__global__ void k_scanC(int* __restrict__ rowptr, const int* __restrict__ bsums) {
  int g = blockIdx.x * 256 + threadIdx.x;
  if (g < NN) rowptr[g] += bsums[blockIdx.x];
  if (g == 0) rowptr[NN] = EE;
}

// pack src (18b) | a9 (4b) | xcode_src (4b)
__global__ void k_fill(const int* __restrict__ ei, const int* __restrict__ ea,
                       const int* __restrict__ xcode, int* __restrict__ cursor,
                       int* __restrict__ eslot) {
  int e = blockIdx.x * 256 + threadIdx.x;
  if (e < EE) {
    int dst = ei[EE + e];
    int src = ei[e];
    int a9 = ea[2 * e] * 3 + ea[2 * e + 1];
    int sc = xcode[src];
    int pos = atomicAdd(&cursor[dst], 1);
    eslot[pos] = src | (a9 << 18) | (sc << 22);
  }
}

// ---------------- fused layer: gather->LDS, MLP (2x MFMA), BN stats ----------------
// Block = 256 threads = 4 waves; block owns 64 consecutive nodes.
// Gather: wave w handles 16 nodes as 4 groups of 4; sub-group (16 lanes) per node,
// uint4 (16B) row loads -> 4 independent edge-row loads in flight per wave.
__global__ __launch_bounds__(256) void k_layer(
    const ushort* __restrict__ zin, ushort* __restrict__ zout,
    const int* __restrict__ xcode, const float* __restrict__ tab,
    const float* __restrict__ bnscale, const float* __restrict__ bnshift,
    const int* __restrict__ rowptr, const int* __restrict__ eslot,
    const ushort* __restrict__ w1s, const ushort* __restrict__ w2s,
    const float* __restrict__ b1, const float* __restrict__ b2,
    float* __restrict__ stats, int layer) {
  __shared__ __align__(16) ushort AGG[64 * 136];
  __shared__ __align__(16) ushort T1[64 * 264];
  const int tid = threadIdx.x;
  const int w = tid >> 6, lane = tid & 63;
  const int ln16 = lane & 15, sub = lane >> 4;
  const int row0 = blockIdx.x * 64;

  // ---- gather phase ----
  const float4* combL4 = (const float4*)(tab + (size_t)layer * 1152);
  const float4* at4 = (const float4*)(tab + 6400);
  const float4* sfp = (const float4*)(tab + 5760 + layer * 128);
  float4 sf0 = sfp[ln16 * 2], sf1 = sfp[ln16 * 2 + 1];
  float4 scv0 = {}, scv1 = {}, shv0 = {}, shv1 = {};
  if (layer > 0) {
    const float4* scp = (const float4*)(bnscale + (layer - 1) * 128);
    const float4* shp = (const float4*)(bnshift + (layer - 1) * 128);
    scv0 = scp[ln16 * 2];
    scv1 = scp[ln16 * 2 + 1];
    shv0 = shp[ln16 * 2];
    shv1 = shp[ln16 * 2 + 1];
  }
  const uint4* z4 = (const uint4*)zin;

  for (int grp = 0; grp < 4; ++grp) {
    const int n = row0 + w * 16 + grp * 4 + sub;
    const int s = rowptr[n], e = rowptr[n + 1];
    float a[8];
    if (layer == 0) {
      int code = xcode[n];
      float4 h0 = at4[code * 32 + ln16 * 2], h1 = at4[code * 32 + ln16 * 2 + 1];
      a[0] = h0.x + sf0.x; a[1] = h0.y + sf0.y; a[2] = h0.z + sf0.z; a[3] = h0.w + sf0.w;
      a[4] = h1.x + sf1.x; a[5] = h1.y + sf1.y; a[6] = h1.z + sf1.z; a[7] = h1.w + sf1.w;
    } else {
      uint4 su = z4[(size_t)n * 16 + ln16];
      a[0] = fmaxf(fmaf(bflo(su.x), scv0.x, shv0.x), 0.f) + sf0.x;
      a[1] = fmaxf(fmaf(bfhi(su.x), scv0.y, shv0.y), 0.f) + sf0.y;
      a[2] = fmaxf(fmaf(bflo(su.y), scv0.z, shv0.z), 0.f) + sf0.z;
      a[3] = fmaxf(fmaf(bfhi(su.y), scv0.w, shv0.w), 0.f) + sf0.w;
      a[4] = fmaxf(fmaf(bflo(su.z), scv1.x, shv1.x), 0.f) + sf1.x;
      a[5] = fmaxf(fmaf(bfhi(su.z), scv1.y, shv1.y), 0.f) + sf1.y;
      a[6] = fmaxf(fmaf(bflo(su.w), scv1.z, shv1.z), 0.f) + sf1.z;
      a[7] = fmaxf(fmaf(bfhi(su.w), scv1.w, shv1.w), 0.f) + sf1.w;
    }
    for (int base = s; base < e; base += 16) {
      int m = e - base;
      if (m > 16) m = 16;
      int slot = (ln16 < m) ? eslot[base + ln16] : 0;
      for (int j = 0; j < m; ++j) {
        int sl = __shfl(slot, sub * 16 + j, 64);
        int a9 = (sl >> 18) & 15;
        float4 cb0 = combL4[a9 * 32 + ln16 * 2], cb1 = combL4[a9 * 32 + ln16 * 2 + 1];
        if (layer == 0) {
          int scode = (sl >> 22) & 15;
          float4 h0 = at4[scode * 32 + ln16 * 2], h1 = at4[scode * 32 + ln16 * 2 + 1];
          a[0] += h0.x + cb0.x; a[1] += h0.y + cb0.y;
          a[2] += h0.z + cb0.z; a[3] += h0.w + cb0.w;
          a[4] += h1.x + cb1.x; a[5] += h1.y + cb1.y;
          a[6] += h1.z + cb1.z; a[7] += h1.w + cb1.w;
        } else {
          int src = sl & 0x3FFFF;
          uint4 u = z4[(size_t)src * 16 + ln16];
          a[0] += fmaxf(fmaf(bflo(u.x), scv0.x, shv0.x), 0.f) + cb0.x;
          a[1] += fmaxf(fmaf(bfhi(u.x), scv0.y, shv0.y), 0.f) + cb0.y;
          a[2] += fmaxf(fmaf(bflo(u.y), scv0.z, shv0.z), 0.f) + cb0.z;
          a[3] += fmaxf(fmaf(bfhi(u.y), scv0.w, shv0.w), 0.f) + cb0.w;
          a[4] += fmaxf(fmaf(bflo(u.z), scv1.x, shv1.x), 0.f) + cb1.x;
          a[5] += fmaxf(fmaf(bfhi(u.z), scv1.y, shv1.y), 0.f) + cb1.y;
          a[6] += fmaxf(fmaf(bflo(u.w), scv1.z, shv1.z), 0.f) + cb1.z;
          a[7] += fmaxf(fmaf(bfhi(u.w), scv1.w, shv1.w), 0.f) + cb1.w;
        }
      }
    }
    uint o0 = (uint)f2bf(a[0]) | ((uint)f2bf(a[1]) << 16);
    uint o1 = (uint)f2bf(a[2]) | ((uint)f2bf(a[3]) << 16);
    uint o2 = (uint)f2bf(a[4]) | ((uint)f2bf(a[5]) << 16);
    uint o3 = (uint)f2bf(a[6]) | ((uint)f2bf(a[7]) << 16);
    uint4 ov = {o0, o1, o2, o3};
    *(uint4*)&AGG[(w * 16 + grp * 4 + sub) * 136 + ln16 * 8] = ov;
  }
  __syncthreads();

  // ---- MLP stage 1: T1 = relu(AGG @ W1 + b1) ----
  const int lm = ln16, q = sub;
  f32x4 acc[4][4] = {};
  const ushort* w1b = w1s + layer * 64 * 512;
#pragma unroll
  for (int kt = 0; kt < 4; ++kt) {
    bf16x8 af[4], bf[4];
#pragma unroll
    for (int mt = 0; mt < 4; ++mt) {
      const ushort* p = AGG + (mt * 16 + lm) * 136 + kt * 32 + q * 8;
      af[mt] = __builtin_bit_cast(bf16x8, *(const ushort8*)p);
    }
#pragma unroll
    for (int nt = 0; nt < 4; ++nt) {
      const ushort* p = w1b + (kt * 16 + w * 4 + nt) * 512 + lane * 8;
      bf[nt] = __builtin_bit_cast(bf16x8, *(const ushort8*)p);
    }
#pragma unroll
    for (int mt = 0; mt < 4; ++mt)
#pragma unroll
      for (int nt = 0; nt < 4; ++nt)
        acc[mt][nt] = __builtin_amdgcn_mfma_f32_16x16x32_bf16(af[mt], bf[nt], acc[mt][nt], 0, 0, 0);
  }
#pragma unroll
  for (int nt = 0; nt < 4; ++nt) {
    int n = w * 64 + nt * 16 + lm;
    float bias = b1[layer * 256 + n];
#pragma unroll
    for (int mt = 0; mt < 4; ++mt)
#pragma unroll
      for (int r = 0; r < 4; ++r) {
        float v = fmaxf(acc[mt][nt][r] + bias, 0.0f);
        T1[(mt * 16 + q * 4 + r) * 264 + n] = f2bf(v);
      }
  }
  __syncthreads();

  // ---- MLP stage 2: z = T1 @ W2 + b2, + BN stats epilogue ----
  f32x4 acc2[4][2] = {};
  const ushort* w2b = w2s + layer * 64 * 512;
#pragma unroll
  for (int kt = 0; kt < 8; ++kt) {
    bf16x8 af[4], bf[2];
#pragma unroll
    for (int mt = 0; mt < 4; ++mt) {
      const ushort* p = T1 + (mt * 16 + lm) * 264 + kt * 32 + q * 8;
      af[mt] = __builtin_bit_cast(bf16x8, *(const ushort8*)p);
    }
#pragma unroll
    for (int nt = 0; nt < 2; ++nt) {
      const ushort* p = w2b + (kt * 8 + w * 2 + nt) * 512 + lane * 8;
      bf[nt] = __builtin_bit_cast(bf16x8, *(const ushort8*)p);
    }
#pragma unroll
    for (int mt = 0; mt < 4; ++mt)
#pragma unroll
      for (int nt = 0; nt < 2; ++nt)
        acc2[mt][nt] = __builtin_amdgcn_mfma_f32_16x16x32_bf16(af[mt], bf[nt], acc2[mt][nt], 0, 0, 0);
  }
  __syncthreads();
  ushort* ldsZ = T1;  // 64 x 136 bf16
  float ssum[2], ssq[2];
#pragma unroll
  for (int nt = 0; nt < 2; ++nt) {
    int n = w * 32 + nt * 16 + lm;
    float bias = b2[layer * 128 + n];
    ssum[nt] = 0.f;
    ssq[nt] = 0.f;
#pragma unroll
    for (int mt = 0; mt < 4; ++mt)
#pragma unroll
      for (int r = 0; r < 4; ++r) {
        float v = acc2[mt][nt][r] + bias;
        ldsZ[(mt * 16 + q * 4 + r) * 136 + n] = f2bf(v);
        ssum[nt] += v;
        ssq[nt] += v * v;
      }
    ssum[nt] += __shfl_xor(ssum[nt], 16, 64);
    ssum[nt] += __shfl_xor(ssum[nt], 32, 64);
    ssq[nt] += __shfl_xor(ssq[nt], 16, 64);
    ssq[nt] += __shfl_xor(ssq[nt], 32, 64);
  }
  if (lane < 16) {
    int cp = blockIdx.x & 15;
    float* sb = stats + (size_t)(layer * 16 + cp) * 256;
#pragma unroll
    for (int nt = 0; nt < 2; ++nt) {
      int col = w * 32 + nt * 16 + lane;
      atomicAdd(&sb[col], ssum[nt]);
      atomicAdd(&sb[128 + col], ssq[nt]);
    }
  }
  __syncthreads();
  uint* zo = (uint*)zout;
  for (int i = tid; i < 64 * 64; i += 256) {
    int row = i >> 6, cpx = i & 63;
    uint v = *(const uint*)&ldsZ[row * 136 + cpx * 2];
    zo[(size_t)(row0 + row) * 64 + cpx] = v;
  }
}

__global__ void k_bnparam(const float* __restrict__ stats, const float* __restrict__ gamma,
                          const float* __restrict__ beta, float* __restrict__ bnscale,
                          float* __restrict__ bnshift, int layer) {
  int c = threadIdx.x;
  float s = 0.f, qv = 0.f;
  for (int cp = 0; cp < 16; ++cp) {
    const float* sb = stats + (size_t)(layer * 16 + cp) * 256;
    s += sb[c];
    qv += sb[128 + c];
  }
  float mu = s * (1.0f / NN);
  float var = qv * (1.0f / NN) - mu * mu;
  float sc = gamma[layer * 128 + c] * rsqrtf(var + 1e-5f);
  bnscale[layer * 128 + c] = sc;
  bnshift[layer * 128 + c] = beta[layer * 128 + c] - mu * sc;
}

// ---------------- pooling with segmented running sum (batch sorted) ----------------
__global__ void k_outinit(float* __restrict__ out, const float* __restrict__ bp) {
  int g = blockIdx.x * 256 + threadIdx.x;
  if (g < GG) out[g] = bp[0];
}

__global__ __launch_bounds__(256) void k_pool(const ushort* __restrict__ z,
                                              const float* __restrict__ bnscale,
                                              const float* __restrict__ bnshift,
                                              const int* __restrict__ batch,
                                              const float* __restrict__ Wp,
                                              float* __restrict__ out) {
  const int tid = threadIdx.x;
  const int w = tid >> 6, lane = tid & 63;
  const int nb = blockIdx.x * 64 + w * 16;
  float2 wp = ((const float2*)Wp)[lane];
  float2 scv = ((const float2*)(bnscale + 4 * 128))[lane];
  float2 shv = ((const float2*)(bnshift + 4 * 128))[lane];
  const uint* z32 = (const uint*)z;
  int bb = (lane < 16) ? batch[nb + lane] : 0;
  int curb = __shfl(bb, 0);
  float run = 0.f;
#pragma unroll
  for (int i = 0; i < 16; ++i) {
    int b = __shfl(bb, i);
    uint u = z32[(size_t)(nb + i) * 64 + lane];
    float dot = fmaf(bflo(u), scv.x, shv.x) * wp.x + fmaf(bfhi(u), scv.y, shv.y) * wp.y;
#pragma unroll
    for (int off = 32; off > 0; off >>= 1) dot += __shfl_xor(dot, off, 64);
    if (b != curb) {
      if (lane == 0) atomicAdd(&out[curb], run);
      run = 0.f;
      curb = b;
    }
    run += dot;
  }
  if (lane == 0) atomicAdd(&out[curb], run);
}

extern "C" void kernel_launch(void* const* d_in, const int* in_sizes, int n_in,
                              void* d_out, int out_size, void* d_ws, size_t ws_size,
                              hipStream_t stream) {
  (void)in_sizes; (void)n_in; (void)out_size; (void)ws_size;
  const int* xidx = (const int*)d_in[0];
  const int* eidx = (const int*)d_in[1];
  const int* eattr = (const int*)d_in[2];
  const int* batch = (const int*)d_in[3];
  const float* at1 = (const float*)d_in[4];
  const float* at2 = (const float*)d_in[5];
  const float* ee1 = (const float*)d_in[6];
  const float* ee2 = (const float*)d_in[7];
  const float* W1 = (const float*)d_in[8];
  const float* b1 = (const float*)d_in[9];
  const float* W2 = (const float*)d_in[10];
  const float* b2 = (const float*)d_in[11];
  const float* gamma = (const float*)d_in[12];
  const float* beta = (const float*)d_in[13];
  const float* Wp = (const float*)d_in[14];
  const float* bp = (const float*)d_in[15];
  float* out = (float*)d_out;

  char* ws = (char*)d_ws;
  size_t off = 0;
  auto alloc = [&](size_t bytes) -> void* {
    void* p = ws + off;
    off = (off + bytes + 255) & ~(size_t)255;
    return p;
  };
  ushort* bufA = (ushort*)alloc((size_t)NN * 128 * 2);
  ushort* bufB = (ushort*)alloc((size_t)NN * 128 * 2);
  ushort* w1s = (ushort*)alloc(320 * 512 * 2);
  ushort* w2s = (ushort*)alloc(320 * 512 * 2);
  int* rowptr = (int*)alloc((NN + 1) * 4);
  int* cursor = (int*)alloc((size_t)NN * 4);
  int* eslot = (int*)alloc((size_t)EE * 4);
  int* bsums = (int*)alloc(1024 * 4);
  float* tab = (float*)alloc(7552 * 4);
  int* xcode = (int*)alloc((size_t)NN * 4);
  float* stats = (float*)alloc((size_t)LL * 16 * 256 * 4);
  float* bnscale = (float*)alloc(LL * 128 * 4);
  float* bnshift = (float*)alloc(LL * 128 * 4);

  hipMemsetAsync(cursor, 0, (size_t)NN * 4, stream);
  hipMemsetAsync(stats, 0, (size_t)LL * 16 * 256 * 4, stream);
  k_swz<<<160, 256, 0, stream>>>(W1, W2, w1s, w2s);
  k_tables<<<30, 256, 0, stream>>>(ee1, ee2, at1, at2, tab);
  k_xcode<<<(NN + 255) / 256, 256, 0, stream>>>(xidx, xcode);
  k_outinit<<<(GG + 255) / 256, 256, 0, stream>>>(out, bp);
  k_count<<<(EE + 255) / 256, 256, 0, stream>>>(eidx, cursor);
  k_scanA<<<SCAN_NB, 256, 0, stream>>>(cursor, rowptr, bsums);
  k_scanB<<<1, 1024, 0, stream>>>(bsums);
  k_scanC<<<SCAN_NB, 256, 0, stream>>>(rowptr, bsums);
  hipMemcpyAsync(cursor, rowptr, (size_t)NN * 4, hipMemcpyDeviceToDevice, stream);
  k_fill<<<(EE + 255) / 256, 256, 0, stream>>>(eidx, eattr, xcode, cursor, eslot);

  for (int l = 0; l < LL; ++l) {
    ushort* zo = (l & 1) ? bufB : bufA;
    const ushort* zi = (l & 1) ? bufA : bufB;  // z_{l-1}; unused for l==0
    k_layer<<<NN / 64, 256, 0, stream>>>((l == 0) ? bufA : zi, zo, xcode, tab, bnscale,
                                         bnshift, rowptr, eslot, w1s, w2s, b1, b2,
                                         stats, l);
    k_bnparam<<<1, 128, 0, stream>>>(stats, gamma, beta, bnscale, bnshift, l);
  }
  k_pool<<<NN / 64, 256, 0, stream>>>(bufA, bnscale, bnshift, batch, Wp, out);
}